// Round 12
// baseline (170.503 us; speedup 1.0000x reference)
//
#include <hip/hip_runtime.h>

// Geometry: G=256 graphs x 64 nodes, H=8 heads x D=8, IN_DIM=EDGE_DIM=64
// EF = 1048576 full edges, ES = 262144 sparse edges.
// edge f = b*4096 + i*64 + j (src=i, dst=j); sparse s = b*1024 + j*16 + k, i=(j+1+k)&63.
//
// Staging: d_out eout region: Qs @0, Ks @1048576, Vs @2097152, PEs @3145728.
//          d_ws: scsp [262144*8] @0, M2 [576] @2097152, T [73*64] @2098176.
// NOTE launch_bounds: (X,>=4) caps VGPR at 64 and SPILLS if demand>64 (r2/r3).
// NOTE VGPR>64 at 1024 threads halves waves/SIMD (8->4) -> 1 block/CU. Keep <=64.
// NOTE r11: attn invariant 60us across 4 structures. qkvpe proves 4.6 TB/s is
// reachable; attn's chunked staging kept 1-2 loads in flight/wave (Little's law
// -> 600 GB/s). Fix = thread-own rel prefetch, 16 loads in flight, 0 mid-loop
// barriers. eoutT: s_load weight stream misses 16KB sK$ (Tm=18.7KB) -> LDS bcast.

// qkv half (blocks 0..255) + pe half (blocks 256..767), independent.
__global__ __launch_bounds__(512, 2) void qkvpe_kernel(
    const float* __restrict__ h,
    const float* __restrict__ e,
    const float* __restrict__ Wq, const float* __restrict__ bq,
    const float* __restrict__ Wk, const float* __restrict__ bk,
    const float* __restrict__ Wv, const float* __restrict__ bv,
    const float* __restrict__ Wpe, const float* __restrict__ bpe,
    float* __restrict__ Qs, float* __restrict__ Ks, float* __restrict__ Vs,
    float* __restrict__ PEs)
{
    const int t = threadIdx.x;
    if (blockIdx.x < 256) {
        const int b    = blockIdx.x;
        const int lane = t & 63;
        const int wu   = __builtin_amdgcn_readfirstlane(t >> 6);   // 8 cols per wave
        const float* hrow = h + (size_t)(b * 64 + lane) * 64;
        float accQ[8], accK[8], accV[8];
        #pragma unroll
        for (int cc = 0; cc < 8; ++cc) {
            const int c = wu * 8 + cc;
            accQ[cc] = bq[c]; accK[cc] = bk[c]; accV[cc] = bv[c];
        }
        #pragma unroll 1
        for (int k0 = 0; k0 < 4; ++k0) {
            float hv[16];
            #pragma unroll
            for (int u = 0; u < 4; ++u) {
                const float4 x = ((const float4*)hrow)[k0 * 4 + u];
                hv[u*4+0] = x.x; hv[u*4+1] = x.y; hv[u*4+2] = x.z; hv[u*4+3] = x.w;
            }
            #pragma unroll
            for (int cc = 0; cc < 8; ++cc) {
                const int c = wu * 8 + cc;
                const float* wq  = Wq + c * 64 + k0 * 16;   // wave-uniform -> s_load
                const float* wk  = Wk + c * 64 + k0 * 16;
                const float* wvp = Wv + c * 64 + k0 * 16;
                #pragma unroll
                for (int k = 0; k < 16; ++k) {
                    accQ[cc] = fmaf(hv[k], wq[k],  accQ[cc]);
                    accK[cc] = fmaf(hv[k], wk[k],  accK[cc]);
                    accV[cc] = fmaf(hv[k], wvp[k], accV[cc]);
                }
            }
        }
        const size_t o = (size_t)(b * 64 + lane) * 64 + wu * 8;
        *(float4*)(Qs + o)     = make_float4(accQ[0], accQ[1], accQ[2], accQ[3]);
        *(float4*)(Qs + o + 4) = make_float4(accQ[4], accQ[5], accQ[6], accQ[7]);
        *(float4*)(Ks + o)     = make_float4(accK[0], accK[1], accK[2], accK[3]);
        *(float4*)(Ks + o + 4) = make_float4(accK[4], accK[5], accK[6], accK[7]);
        *(float4*)(Vs + o)     = make_float4(accV[0], accV[1], accV[2], accV[3]);
        *(float4*)(Vs + o + 4) = make_float4(accV[4], accV[5], accV[6], accV[7]);
    } else {
        const int row = (blockIdx.x - 256) * 512 + t;      // 0..ES-1
        const float* erow = e + (size_t)row * 64;
        float acc[8];
        #pragma unroll
        for (int h2 = 0; h2 < 8; ++h2) acc[h2] = bpe[h2];
        #pragma unroll 1
        for (int k0 = 0; k0 < 4; ++k0) {
            float ev[16];
            #pragma unroll
            for (int u = 0; u < 4; ++u) {
                const float4 x = ((const float4*)erow)[k0 * 4 + u];
                ev[u*4+0] = x.x; ev[u*4+1] = x.y; ev[u*4+2] = x.z; ev[u*4+3] = x.w;
            }
            #pragma unroll
            for (int h2 = 0; h2 < 8; ++h2) {
                const float* wp = Wpe + h2 * 64 + k0 * 16;  // uniform -> s_load
                #pragma unroll
                for (int k = 0; k < 16; ++k)
                    acc[h2] = fmaf(ev[k], wp[k], acc[h2]);
            }
        }
        float* p0 = PEs + (size_t)row * 8;
        *(float4*)(p0)     = make_float4(acc[0], acc[1], acc[2], acc[3]);
        *(float4*)(p0 + 4) = make_float4(acc[4], acc[5], acc[6], acc[7]);
    }
}

// Core: 1024 threads = (j_local 0..31, hh 0..7, q4 0..3), i = q4*16 + it.
// rel: 16 thread-own scalar loads -> registers, issued in prologue (4x64B
// fully-utilized segments/wave-load, 4KB/wave MLP). adj: LDS staged ONCE.
// ONE barrier before the loop; loop is pure LDS/VALU.
__global__ __launch_bounds__(1024, 2) void attn_kernel(
    const float* __restrict__ Qs, const float* __restrict__ Ks,
    const float* __restrict__ Vs, const float* __restrict__ PEs,
    const float* __restrict__ adj2,
    const float* __restrict__ rel,
    const float* __restrict__ Wo, const float* __restrict__ bo,
    float* __restrict__ h_out,
    float* __restrict__ scsp)
{
    __shared__ float shK[64 * 64];    // swizzled: row r, colgrp g at r*64+((g^(r&7))<<3)
    __shared__ float shV[64 * 64];    // (shK reused as wV[32][64] after the loop)
    __shared__ float shPE[512 * 8];   // proj_e -> overwritten in-place with sc_sp
    __shared__ float shAdj[64 * 33];  // [i][jl], pad 33

    const int b2   = blockIdx.x;
    const int b    = b2 >> 1;
    const int joff = (b2 & 1) << 5;          // 0 or 32
    const int t    = threadIdx.x;

    const int j_local = t >> 5;              // 0..31
    const int hh      = (t >> 2) & 7;        // 0..7
    const int q4      = t & 3;               // 0..3
    const int j       = joff + j_local;

    // ---- rel register prefetch: thread-own 16 scalars, fully unrolled (rule #20)
    const float* relP = rel + ((size_t)b * 4096 + j) * 8 + hh;   // + i*512
    float R[16];
    #pragma unroll
    for (int it = 0; it < 16; ++it)
        R[it] = relP[(size_t)((q4 << 4) + it) * 512];

    // ---- stage K, V (swizzled), PE, adj (once); Q per-thread
    {
        const int r  = t >> 4;               // 0..63
        const int gh = t & 15;
        const int g  = gh >> 1, lo = (gh & 1) * 4;
        const int d  = r * 64 + ((g ^ (r & 7)) << 3) + lo;
        const int so = r * 64 + g * 8 + lo;
        shK[d + 0] = Ks[(size_t)b * 4096 + so + 0];
        shK[d + 1] = Ks[(size_t)b * 4096 + so + 1];
        shK[d + 2] = Ks[(size_t)b * 4096 + so + 2];
        shK[d + 3] = Ks[(size_t)b * 4096 + so + 3];
        shV[d + 0] = Vs[(size_t)b * 4096 + so + 0];
        shV[d + 1] = Vs[(size_t)b * 4096 + so + 1];
        shV[d + 2] = Vs[(size_t)b * 4096 + so + 2];
        shV[d + 3] = Vs[(size_t)b * 4096 + so + 3];
        *(float4*)&shPE[t * 4] =
            *(const float4*)(PEs + ((size_t)b * 1024 + joff * 16) * 8 + t * 4);
    }
    if (t < 512) {   // adj tile: 64 i x 32 jl, coalesced float4
        const int ia = t >> 3, qq = t & 7;
        const float4 x = *(const float4*)(adj2 + (size_t)b * 4096 + ia * 64 + joff + qq * 4);
        shAdj[ia * 33 + qq * 4 + 0] = x.x;
        shAdj[ia * 33 + qq * 4 + 1] = x.y;
        shAdj[ia * 33 + qq * 4 + 2] = x.z;
        shAdj[ia * 33 + qq * 4 + 3] = x.w;
    }
    float q[8];
    {
        const float* qp = Qs + (size_t)(b * 64 + j) * 64 + hh * 8;
        const float4 a = *(const float4*)qp;
        const float4 c = *(const float4*)(qp + 4);
        q[0]=a.x; q[1]=a.y; q[2]=a.z; q[3]=a.w;
        q[4]=c.x; q[5]=c.y; q[6]=c.z; q[7]=c.w;
    }
    __syncthreads();

    // ---- P3: scores + online softmax over this thread's 16 i's (pure LDS/VALU)
    float den = 0.f;
    float wv[8] = {0.f,0.f,0.f,0.f,0.f,0.f,0.f,0.f};
    const float inv_scale = 0.35355339059327379f;  // 1/sqrt(8)
    #pragma unroll
    for (int it = 0; it < 16; ++it) {
        const int i  = (q4 << 4) + it;
        const float a2 = shAdj[i * 33 + j_local];
        const int kb = i * 64 + ((hh ^ (i & 7)) << 3);
        const float4 kA = *(const float4*)&shK[kb];
        const float4 kB = *(const float4*)&shK[kb + 4];
        float s;
        s = kA.x * q[0];
        s = fmaf(kA.y, q[1], s); s = fmaf(kA.z, q[2], s); s = fmaf(kA.w, q[3], s);
        s = fmaf(kB.x, q[4], s); s = fmaf(kB.y, q[5], s); s = fmaf(kB.z, q[6], s);
        s = fmaf(kB.w, q[7], s);
        s = fmaf(s * inv_scale, a2, R[it]);       // raw score (pre proj_e, unclipped)
        const int kidx = (i - j - 1) & 63;
        if (kidx < 16) {                          // sparse edge (i -> j), unique owner
            const int x = (j_local * 16 + kidx) * 8 + hh;
            const float pe = shPE[x];             // read proj_e once
            shPE[x] = s;                          // overwrite with sc_sp (in-place)
            s += pe;                              // softmax sees sc_sp + proj_e
        }
        s = fminf(fmaxf(s, -5.f), 5.f);
        const float ex = __expf(s);
        den += ex;
        const float4 vA = *(const float4*)&shV[kb];
        const float4 vB = *(const float4*)&shV[kb + 4];
        wv[0] = fmaf(ex, vA.x, wv[0]); wv[1] = fmaf(ex, vA.y, wv[1]);
        wv[2] = fmaf(ex, vA.z, wv[2]); wv[3] = fmaf(ex, vA.w, wv[3]);
        wv[4] = fmaf(ex, vB.x, wv[4]); wv[5] = fmaf(ex, vB.y, wv[5]);
        wv[6] = fmaf(ex, vB.z, wv[6]); wv[7] = fmaf(ex, vB.w, wv[7]);
    }
    // reduce across the 4 i-quarters (lane bits 0-1)
    den += __shfl_xor(den, 1);
    den += __shfl_xor(den, 2);
    #pragma unroll
    for (int u = 0; u < 8; ++u) {
        wv[u] += __shfl_xor(wv[u], 1);
        wv[u] += __shfl_xor(wv[u], 2);
    }
    __syncthreads();                 // all K/V reads + PE->SC swaps complete

    // ---- P4: coalesced sc_sp dump (2 threads per sparse row); wV -> dead shK
    {
        const int row = t >> 1, pp = t & 1;
        *(float4*)(scsp + (size_t)((size_t)b * 1024 + joff * 16 + row) * 8 + pp * 4) =
            *(const float4*)&shPE[row * 8 + pp * 4];
    }
    if (q4 == 0) {
        const float id = 1.f / den;
        float* wp = &shK[j_local * 64 + hh * 8];   // shK := wV[32][64], plain layout
        *(float4*)(wp)     = make_float4(wv[0]*id, wv[1]*id, wv[2]*id, wv[3]*id);
        *(float4*)(wp + 4) = make_float4(wv[4]*id, wv[5]*id, wv[6]*id, wv[7]*id);
    }
    __syncthreads();

    // ---- P5: h_out = wV @ Wo^T + bo. thread = (rl = t>>5, c0 = (t&31)*2), 2 cols
    {
        const int rl = t >> 5;
        const int c0 = (t & 31) * 2;
        float acc[2];
        acc[0] = bo[c0]; acc[1] = bo[c0 + 1];
        #pragma unroll 1
        for (int k0 = 0; k0 < 4; ++k0) {
            float tv[16];
            #pragma unroll
            for (int u = 0; u < 4; ++u) {
                const float4 x = *(const float4*)&shK[rl * 64 + k0 * 16 + u * 4];
                tv[u*4+0] = x.x; tv[u*4+1] = x.y; tv[u*4+2] = x.z; tv[u*4+3] = x.w;
            }
            #pragma unroll
            for (int u = 0; u < 2; ++u) {
                const float* wo = Wo + (c0 + u) * 64 + k0 * 16;
                #pragma unroll
                for (int k = 0; k < 16; ++k)
                    acc[u] = fmaf(tv[k], wo[k], acc[u]);
            }
        }
        float* orow = h_out + (size_t)(b * 64 + joff + rl) * 64 + c0;
        *(float2*)orow = make_float2(acc[0], acc[1]);
    }
}

// prep: M2/bc (fallback) + T[73][64] = [Woe^T ; M2^T ; bc].
__global__ void prep_kernel(const float* __restrict__ Wap, const float* __restrict__ bap,
                            const float* __restrict__ Woe, const float* __restrict__ boe,
                            float* __restrict__ M2, float* __restrict__ Tm, int hasT)
{
    const int tg = blockIdx.x * 64 + threadIdx.x;
    if (tg < 512) {
        const int c = tg >> 3, hq = tg & 7;
        float s = 0.f;
        #pragma unroll 8
        for (int k = 0; k < 64; ++k) s = fmaf(Woe[c * 64 + k], Wap[k * 8 + hq], s);
        M2[tg] = s;
    } else if (tg < 576) {
        const int c = tg - 512;
        float s = boe[c];
        #pragma unroll 8
        for (int k = 0; k < 64; ++k) s = fmaf(bap[k], Woe[c * 64 + k], s);
        M2[512 + c] = s;
    } else if (hasT && tg < 576 + 73 * 64) {
        const int idx = tg - 576;
        const int k = idx >> 6, c = idx & 63;
        float v;
        if (k < 64) {
            v = Woe[c * 64 + k];
        } else if (k < 72) {
            const int hq = k - 64;
            v = 0.f;
            #pragma unroll 8
            for (int kk = 0; kk < 64; ++kk)
                v = fmaf(Woe[c * 64 + kk], Wap[kk * 8 + hq], v);
        } else {
            v = boe[c];
            #pragma unroll 8
            for (int kk = 0; kk < 64; ++kk)
                v = fmaf(bap[kk], Woe[c * 64 + kk], v);
        }
        Tm[k * 64 + c] = v;
    }
}

// eoutT: k-outer; e^T in LDS (stride 67); WEIGHTS IN LDS (broadcast ds_read_b128,
// same-address across lanes = conflict-free). 16 independent FMAs per k.
__global__ __launch_bounds__(256, 2) void eoutT_kernel(
    const float* __restrict__ e,
    const float* __restrict__ scsp,
    const float* __restrict__ Tm,      // [73][64]: Woe^T, M2^T, bc
    float* __restrict__ e_out)
{
    __shared__ float shET[64 * 67];   // [c][r] stride 67
    __shared__ float shS[64 * 8];
    __shared__ float shT[73 * 64];    // weights + bc, 18.7 KB

    const int t    = threadIdx.x;
    const int base = blockIdx.x * 64;

    {   // coop e-tile load (coalesced) -> transposed LDS store
        const int r0 = t >> 2, qq = t & 3;
        const float* ep = e + (size_t)(base + r0) * 64 + qq * 16;
        #pragma unroll
        for (int v = 0; v < 4; ++v) {
            const float4 x = ((const float4*)ep)[v];
            const int c = qq * 16 + v * 4;
            shET[(c + 0) * 67 + r0] = x.x;
            shET[(c + 1) * 67 + r0] = x.y;
            shET[(c + 2) * 67 + r0] = x.z;
            shET[(c + 3) * 67 + r0] = x.w;
        }
    }
    if (t < 128) {
        const int r = t >> 1, pp = t & 1;
        *(float4*)&shS[r * 8 + pp * 4] =
            *(const float4*)(scsp + (size_t)(base + r) * 8 + pp * 4);
    }
    #pragma unroll
    for (int v = 0; v < 5; ++v) {     // 73*64/4 = 1168 float4
        const int fi = v * 256 + t;
        if (fi < 1168)
            *(float4*)&shT[fi * 4] = *(const float4*)(Tm + fi * 4);
    }
    __syncthreads();

    const int w = __builtin_amdgcn_readfirstlane(t >> 6);  // col group, uniform
    const int r = t & 63;

    float sc[8];
    {
        const float4 a  = *(const float4*)&shS[r * 8];
        const float4 c4 = *(const float4*)&shS[r * 8 + 4];
        sc[0]=a.x; sc[1]=a.y; sc[2]=a.z; sc[3]=a.w;
        sc[4]=c4.x; sc[5]=c4.y; sc[6]=c4.z; sc[7]=c4.w;
    }
    float acc[16];
    {
        const float4 b0 = *(const float4*)&shT[72 * 64 + w * 16];
        const float4 b1 = *(const float4*)&shT[72 * 64 + w * 16 + 4];
        const float4 b2 = *(const float4*)&shT[72 * 64 + w * 16 + 8];
        const float4 b3 = *(const float4*)&shT[72 * 64 + w * 16 + 12];
        acc[0]=b0.x; acc[1]=b0.y; acc[2]=b0.z; acc[3]=b0.w;
        acc[4]=b1.x; acc[5]=b1.y; acc[6]=b1.z; acc[7]=b1.w;
        acc[8]=b2.x; acc[9]=b2.y; acc[10]=b2.z; acc[11]=b2.w;
        acc[12]=b3.x; acc[13]=b3.y; acc[14]=b3.z; acc[15]=b3.w;
    }
    #pragma unroll
    for (int k = 0; k < 64; ++k) {
        const float evk = shET[k * 67 + r];                 // 2 lanes/bank: free
        const float4 w0 = *(const float4*)&shT[k * 64 + w * 16];      // broadcast
        const float4 w1 = *(const float4*)&shT[k * 64 + w * 16 + 4];
        const float4 w2 = *(const float4*)&shT[k * 64 + w * 16 + 8];
        const float4 w3 = *(const float4*)&shT[k * 64 + w * 16 + 12];
        acc[0]  = fmaf(evk, w0.x, acc[0]);  acc[1]  = fmaf(evk, w0.y, acc[1]);
        acc[2]  = fmaf(evk, w0.z, acc[2]);  acc[3]  = fmaf(evk, w0.w, acc[3]);
        acc[4]  = fmaf(evk, w1.x, acc[4]);  acc[5]  = fmaf(evk, w1.y, acc[5]);
        acc[6]  = fmaf(evk, w1.z, acc[6]);  acc[7]  = fmaf(evk, w1.w, acc[7]);
        acc[8]  = fmaf(evk, w2.x, acc[8]);  acc[9]  = fmaf(evk, w2.y, acc[9]);
        acc[10] = fmaf(evk, w2.z, acc[10]); acc[11] = fmaf(evk, w2.w, acc[11]);
        acc[12] = fmaf(evk, w3.x, acc[12]); acc[13] = fmaf(evk, w3.y, acc[13]);
        acc[14] = fmaf(evk, w3.z, acc[14]); acc[15] = fmaf(evk, w3.w, acc[15]);
    }
    #pragma unroll
    for (int hq = 0; hq < 8; ++hq) {
        const float sk = sc[hq];
        const float4 w0 = *(const float4*)&shT[(64 + hq) * 64 + w * 16];
        const float4 w1 = *(const float4*)&shT[(64 + hq) * 64 + w * 16 + 4];
        const float4 w2 = *(const float4*)&shT[(64 + hq) * 64 + w * 16 + 8];
        const float4 w3 = *(const float4*)&shT[(64 + hq) * 64 + w * 16 + 12];
        acc[0]  = fmaf(sk, w0.x, acc[0]);  acc[1]  = fmaf(sk, w0.y, acc[1]);
        acc[2]  = fmaf(sk, w0.z, acc[2]);  acc[3]  = fmaf(sk, w0.w, acc[3]);
        acc[4]  = fmaf(sk, w1.x, acc[4]);  acc[5]  = fmaf(sk, w1.y, acc[5]);
        acc[6]  = fmaf(sk, w1.z, acc[6]);  acc[7]  = fmaf(sk, w1.w, acc[7]);
        acc[8]  = fmaf(sk, w2.x, acc[8]);  acc[9]  = fmaf(sk, w2.y, acc[9]);
        acc[10] = fmaf(sk, w2.z, acc[10]); acc[11] = fmaf(sk, w2.w, acc[11]);
        acc[12] = fmaf(sk, w3.x, acc[12]); acc[13] = fmaf(sk, w3.y, acc[13]);
        acc[14] = fmaf(sk, w3.z, acc[14]); acc[15] = fmaf(sk, w3.w, acc[15]);
    }
    float* orow = e_out + (size_t)(base + r) * 64 + w * 16;
    #pragma unroll
    for (int u = 0; u < 4; ++u)
        *(float4*)&orow[u * 4] =
            make_float4(acc[u*4+0], acc[u*4+1], acc[u*4+2], acc[u*4+3]);
}

// Fallback eout (r10 shape) if d_ws can't hold T.
__global__ __launch_bounds__(256, 2) void eout_kernel(
    const float* __restrict__ e,
    const float* __restrict__ scsp,
    const float* __restrict__ Woe,
    const float* __restrict__ M2g,
    float* __restrict__ e_out)
{
    __shared__ float shE[64 * 64];
    __shared__ float shS[64 * 8];
    const int t    = threadIdx.x;
    const int base = blockIdx.x * 64;
    {
        const int r = t >> 2, qq = t & 3;
        const float* ep = e + (size_t)(base + r) * 64 + qq * 16;
        #pragma unroll
        for (int u = 0; u < 4; ++u) {
            const float4 x = ((const float4*)ep)[u];
            const int cc = qq * 4 + u;
            *(float4*)&shE[r * 64 + ((cc ^ (r & 15)) << 2)] = x;
        }
    }
    if (t < 128) {
        const int r = t >> 1, pp = t & 1;
        *(float4*)&shS[r * 8 + pp * 4] =
            *(const float4*)(scsp + (size_t)(base + r) * 8 + pp * 4);
    }
    __syncthreads();
    const int w = __builtin_amdgcn_readfirstlane(t >> 6);
    const int r = t & 63;
    float sc[8];
    {
        const float4 a  = *(const float4*)&shS[r * 8];
        const float4 c4 = *(const float4*)&shS[r * 8 + 4];
        sc[0]=a.x; sc[1]=a.y; sc[2]=a.z; sc[3]=a.w;
        sc[4]=c4.x; sc[5]=c4.y; sc[6]=c4.z; sc[7]=c4.w;
    }
    float acc[16];
    #pragma unroll
    for (int u = 0; u < 16; ++u) {
        const int c = w * 16 + u;
        float s = M2g[512 + c];
        #pragma unroll
        for (int hq = 0; hq < 8; ++hq)
            s = fmaf(sc[hq], M2g[c * 8 + hq], s);
        acc[u] = s;
    }
    #pragma unroll
    for (int k0 = 0; k0 < 4; ++k0) {
        float ev[16];
        #pragma unroll
        for (int v = 0; v < 4; ++v) {
            const int cc = k0 * 4 + v;
            const float4 x = *(const float4*)&shE[r * 64 + ((cc ^ (r & 15)) << 2)];
            ev[v*4+0] = x.x; ev[v*4+1] = x.y; ev[v*4+2] = x.z; ev[v*4+3] = x.w;
        }
        #pragma unroll
        for (int u = 0; u < 16; ++u) {
            const float* wr = Woe + (w * 16 + u) * 64 + k0 * 16;
            #pragma unroll
            for (int k = 0; k < 16; ++k)
                acc[u] = fmaf(ev[k], wr[k], acc[u]);
        }
    }
    float* orow = e_out + (size_t)(base + r) * 64 + w * 16;
    #pragma unroll
    for (int u = 0; u < 4; ++u)
        *(float4*)&orow[u * 4] =
            make_float4(acc[u*4+0], acc[u*4+1], acc[u*4+2], acc[u*4+3]);
}

extern "C" void kernel_launch(void* const* d_in, const int* in_sizes, int n_in,
                              void* d_out, int out_size, void* d_ws, size_t ws_size,
                              hipStream_t stream) {
    const float* h    = (const float*)d_in[0];
    const float* e    = (const float*)d_in[1];
    const float* adj2 = (const float*)d_in[2];
    const float* rel  = (const float*)d_in[3];
    const float* Wq   = (const float*)d_in[4];  const float* bq  = (const float*)d_in[5];
    const float* Wk   = (const float*)d_in[6];  const float* bk  = (const float*)d_in[7];
    const float* Wv   = (const float*)d_in[8];  const float* bv  = (const float*)d_in[9];
    const float* Wpe  = (const float*)d_in[10]; const float* bpe = (const float*)d_in[11];
    const float* Wap  = (const float*)d_in[12]; const float* bap = (const float*)d_in[13];
    const float* Wo   = (const float*)d_in[14]; const float* bo  = (const float*)d_in[15];
    const float* Woe  = (const float*)d_in[16]; const float* boe = (const float*)d_in[17];

    float* out  = (float*)d_out;
    float* hout = out;                        // [16384*64]
    float* eout = out + 16384 * 64;           // [262144*64], staging (dead at eout time)
    float* Qs   = eout;                       // 1048576 floats
    float* Ks   = eout + 1048576;
    float* Vs   = eout + 2097152;
    float* PEs  = eout + 3145728;             // 2097152 floats
    float* ws   = (float*)d_ws;
    float* scsp = ws;                         // [262144*8]
    float* M2g  = ws + 2097152;               // [576]
    float* Tm   = ws + 2098176;               // [73*64]
    const int hasT = (ws_size >= (size_t)(2098176 + 73 * 64) * sizeof(float)) ? 1 : 0;

    prep_kernel<<<dim3(82), dim3(64), 0, stream>>>(Wap, bap, Woe, boe, M2g, Tm, hasT);
    qkvpe_kernel<<<dim3(768), dim3(512), 0, stream>>>(
        h, e, Wq, bq, Wk, bk, Wv, bv, Wpe, bpe, Qs, Ks, Vs, PEs);
    attn_kernel<<<dim3(512), dim3(1024), 0, stream>>>(
        Qs, Ks, Vs, PEs, adj2, rel, Wo, bo, hout, scsp);
    if (hasT)
        eoutT_kernel<<<dim3(4096), dim3(256), 0, stream>>>(e, scsp, Tm, eout);
    else
        eout_kernel<<<dim3(4096), dim3(256), 0, stream>>>(e, scsp, Woe, M2g, eout);
}

// Round 13
// 130.943 us; speedup vs baseline: 1.3021x; 1.3021x over previous
//
#include <hip/hip_runtime.h>

// Geometry: G=256 graphs x 64 nodes, H=8 heads x D=8, IN_DIM=EDGE_DIM=64
// EF = 1048576 full edges, ES = 262144 sparse edges.
// edge f = b*4096 + i*64 + j (src=i, dst=j); sparse s = b*1024 + j*16 + k, i=(j+1+k)&63.
//
// Staging: d_out eout region: Qs @0, Ks @1048576, Vs @2097152, PEs @3145728.
//          d_ws: scsp [262144*8] @0, M2 [576] @2097152, T [73*64] @2098176.
// NOTE launch_bounds: VGPR cap = 2048/(threads/64 * minwaves); spills if exceeded
// (r2/r3/r12: WRITE_SIZE blowup = spill alarm). 1024thr/(,2) -> 64 cap.
// NOTE r12 diagnosis: attn's 60us invariant = LDS bank conflicts. Lanes within a
// wave carried DIFFERENT i; i*64 = 0 mod 32 banks -> 4 i-rows alias -> 4-way
// conflict on every K/V b128 + one LDS unit/CU serializes (~40us). Fix: thread
// map t = q4*256 + jl*8 + hh -> wave-uniform i (broadcast row, 8 colgrps, 2-way
// = free). Same for eoutT: 4xb128 BROADCAST weight reads/k -> 4x4 micro-tile
// (2 bank-spread b128 per 16 FMAs).

// qkv half (blocks 0..255) + pe half (blocks 256..767), independent.
__global__ __launch_bounds__(512, 2) void qkvpe_kernel(
    const float* __restrict__ h,
    const float* __restrict__ e,
    const float* __restrict__ Wq, const float* __restrict__ bq,
    const float* __restrict__ Wk, const float* __restrict__ bk,
    const float* __restrict__ Wv, const float* __restrict__ bv,
    const float* __restrict__ Wpe, const float* __restrict__ bpe,
    float* __restrict__ Qs, float* __restrict__ Ks, float* __restrict__ Vs,
    float* __restrict__ PEs)
{
    const int t = threadIdx.x;
    if (blockIdx.x < 256) {
        const int b    = blockIdx.x;
        const int lane = t & 63;
        const int wu   = __builtin_amdgcn_readfirstlane(t >> 6);   // 8 cols per wave
        const float* hrow = h + (size_t)(b * 64 + lane) * 64;
        float accQ[8], accK[8], accV[8];
        #pragma unroll
        for (int cc = 0; cc < 8; ++cc) {
            const int c = wu * 8 + cc;
            accQ[cc] = bq[c]; accK[cc] = bk[c]; accV[cc] = bv[c];
        }
        #pragma unroll 1
        for (int k0 = 0; k0 < 4; ++k0) {
            float hv[16];
            #pragma unroll
            for (int u = 0; u < 4; ++u) {
                const float4 x = ((const float4*)hrow)[k0 * 4 + u];
                hv[u*4+0] = x.x; hv[u*4+1] = x.y; hv[u*4+2] = x.z; hv[u*4+3] = x.w;
            }
            #pragma unroll
            for (int cc = 0; cc < 8; ++cc) {
                const int c = wu * 8 + cc;
                const float* wq  = Wq + c * 64 + k0 * 16;   // wave-uniform -> s_load
                const float* wk  = Wk + c * 64 + k0 * 16;
                const float* wvp = Wv + c * 64 + k0 * 16;
                #pragma unroll
                for (int k = 0; k < 16; ++k) {
                    accQ[cc] = fmaf(hv[k], wq[k],  accQ[cc]);
                    accK[cc] = fmaf(hv[k], wk[k],  accK[cc]);
                    accV[cc] = fmaf(hv[k], wvp[k], accV[cc]);
                }
            }
        }
        const size_t o = (size_t)(b * 64 + lane) * 64 + wu * 8;
        *(float4*)(Qs + o)     = make_float4(accQ[0], accQ[1], accQ[2], accQ[3]);
        *(float4*)(Qs + o + 4) = make_float4(accQ[4], accQ[5], accQ[6], accQ[7]);
        *(float4*)(Ks + o)     = make_float4(accK[0], accK[1], accK[2], accK[3]);
        *(float4*)(Ks + o + 4) = make_float4(accK[4], accK[5], accK[6], accK[7]);
        *(float4*)(Vs + o)     = make_float4(accV[0], accV[1], accV[2], accV[3]);
        *(float4*)(Vs + o + 4) = make_float4(accV[4], accV[5], accV[6], accV[7]);
    } else {
        const int row = (blockIdx.x - 256) * 512 + t;      // 0..ES-1
        const float* erow = e + (size_t)row * 64;
        float acc[8];
        #pragma unroll
        for (int h2 = 0; h2 < 8; ++h2) acc[h2] = bpe[h2];
        #pragma unroll 1
        for (int k0 = 0; k0 < 4; ++k0) {
            float ev[16];
            #pragma unroll
            for (int u = 0; u < 4; ++u) {
                const float4 x = ((const float4*)erow)[k0 * 4 + u];
                ev[u*4+0] = x.x; ev[u*4+1] = x.y; ev[u*4+2] = x.z; ev[u*4+3] = x.w;
            }
            #pragma unroll
            for (int h2 = 0; h2 < 8; ++h2) {
                const float* wp = Wpe + h2 * 64 + k0 * 16;  // uniform -> s_load
                #pragma unroll
                for (int k = 0; k < 16; ++k)
                    acc[h2] = fmaf(ev[k], wp[k], acc[h2]);
            }
        }
        float* p0 = PEs + (size_t)row * 8;
        *(float4*)(p0)     = make_float4(acc[0], acc[1], acc[2], acc[3]);
        *(float4*)(p0 + 4) = make_float4(acc[4], acc[5], acc[6], acc[7]);
    }
}

// Core: 1024 threads, t = q4*256 + j_local*8 + hh -> each wave: ONE i per
// iteration (broadcast LDS rows), rel = one coalesced 256B wave-load/iter.
// Quarter reduction: 4 barrier-ordered passes through shRed (deterministic).
__global__ __launch_bounds__(1024, 2) void attn_kernel(
    const float* __restrict__ Qs, const float* __restrict__ Ks,
    const float* __restrict__ Vs, const float* __restrict__ PEs,
    const float* __restrict__ adj2,
    const float* __restrict__ rel,
    const float* __restrict__ Wo, const float* __restrict__ bo,
    float* __restrict__ h_out,
    float* __restrict__ scsp)
{
    __shared__ float shK[64 * 64];    // swizzled: row r, colgrp g at r*64+((g^(r&7))<<3)
    __shared__ float shV[64 * 64];    // (shK reused as wV[32][64] after the loop)
    __shared__ float shPE[512 * 8];   // proj_e -> overwritten in-place with sc_sp
    __shared__ float shRed[256 * 9];  // cross-wave partials: [jh][wv0..7, den]

    const int b2   = blockIdx.x;
    const int b    = b2 >> 1;
    const int joff = (b2 & 1) << 5;          // 0 or 32
    const int t    = threadIdx.x;

    const int j_local = (t >> 3) & 31;       // 0..31
    const int hh      = t & 7;               // 0..7
    const int q4      = t >> 8;              // 0..3 (i-quarter, = wave group)
    const int j       = joff + j_local;

    // ---- stage K, V (swizzled), PE; Q per-thread
    {
        const int r  = t >> 4;               // 0..63
        const int gh = t & 15;
        const int g  = gh >> 1, lo = (gh & 1) * 4;
        const int d  = r * 64 + ((g ^ (r & 7)) << 3) + lo;
        const int so = r * 64 + g * 8 + lo;
        shK[d + 0] = Ks[(size_t)b * 4096 + so + 0];
        shK[d + 1] = Ks[(size_t)b * 4096 + so + 1];
        shK[d + 2] = Ks[(size_t)b * 4096 + so + 2];
        shK[d + 3] = Ks[(size_t)b * 4096 + so + 3];
        shV[d + 0] = Vs[(size_t)b * 4096 + so + 0];
        shV[d + 1] = Vs[(size_t)b * 4096 + so + 1];
        shV[d + 2] = Vs[(size_t)b * 4096 + so + 2];
        shV[d + 3] = Vs[(size_t)b * 4096 + so + 3];
        *(float4*)&shPE[t * 4] =
            *(const float4*)(PEs + ((size_t)b * 1024 + joff * 16) * 8 + t * 4);
    }
    float q[8];
    {
        const float* qp = Qs + (size_t)(b * 64 + j) * 64 + hh * 8;
        const float4 a = *(const float4*)qp;
        const float4 c = *(const float4*)(qp + 4);
        q[0]=a.x; q[1]=a.y; q[2]=a.z; q[3]=a.w;
        q[4]=c.x; q[5]=c.y; q[6]=c.z; q[7]=c.w;
    }
    __syncthreads();

    // ---- P3: scores + online softmax over this quarter's 16 i's
    // per iteration/wave: rel = 1x coalesced 256B load, adj = 1 broadcast word,
    // K/V = broadcast rows (2-way max = free).
    float den = 0.f;
    float wv[8] = {0.f,0.f,0.f,0.f,0.f,0.f,0.f,0.f};
    const float* relP = rel  + (size_t)b * 32768 + (size_t)(joff + j_local) * 8 + hh;
    const float* adjP = adj2 + (size_t)b * 4096 + j;
    const float inv_scale = 0.35355339059327379f;  // 1/sqrt(8)
    #pragma unroll 4
    for (int it = 0; it < 16; ++it) {
        const int i  = (q4 << 4) + it;            // wave-uniform
        const float rp = relP[(size_t)i * 512];
        const float a2 = adjP[(size_t)i * 64];
        const int kb = i * 64 + ((hh ^ (i & 7)) << 3);
        const float4 kA = *(const float4*)&shK[kb];
        const float4 kB = *(const float4*)&shK[kb + 4];
        float s;
        s = kA.x * q[0];
        s = fmaf(kA.y, q[1], s); s = fmaf(kA.z, q[2], s); s = fmaf(kA.w, q[3], s);
        s = fmaf(kB.x, q[4], s); s = fmaf(kB.y, q[5], s); s = fmaf(kB.z, q[6], s);
        s = fmaf(kB.w, q[7], s);
        s = fmaf(s * inv_scale, a2, rp);          // raw score (pre proj_e, unclipped)
        const int kidx = (i - j - 1) & 63;
        if (kidx < 16) {                          // sparse edge (i -> j), unique owner
            const int x = (j_local * 16 + kidx) * 8 + hh;
            const float pe = shPE[x];             // read proj_e once
            shPE[x] = s;                          // overwrite with sc_sp (in-place)
            s += pe;                              // softmax sees sc_sp + proj_e
        }
        s = fminf(fmaxf(s, -5.f), 5.f);
        const float ex = __expf(s);
        den += ex;
        const float4 vA = *(const float4*)&shV[kb];
        const float4 vB = *(const float4*)&shV[kb + 4];
        wv[0] = fmaf(ex, vA.x, wv[0]); wv[1] = fmaf(ex, vA.y, wv[1]);
        wv[2] = fmaf(ex, vA.z, wv[2]); wv[3] = fmaf(ex, vA.w, wv[3]);
        wv[4] = fmaf(ex, vB.x, wv[4]); wv[5] = fmaf(ex, vB.y, wv[5]);
        wv[6] = fmaf(ex, vB.z, wv[6]); wv[7] = fmaf(ex, vB.w, wv[7]);
    }
    // ---- cross-wave quarter reduction: 4 deterministic barrier-ordered passes
    const int jh = t & 255;                       // j_local*8 + hh
    if (q4 == 0) {
        #pragma unroll
        for (int u = 0; u < 8; ++u) shRed[jh * 9 + u] = wv[u];
        shRed[jh * 9 + 8] = den;
    }
    __syncthreads();
    if (q4 == 1) {
        #pragma unroll
        for (int u = 0; u < 8; ++u) shRed[jh * 9 + u] += wv[u];
        shRed[jh * 9 + 8] += den;
    }
    __syncthreads();
    if (q4 == 2) {
        #pragma unroll
        for (int u = 0; u < 8; ++u) shRed[jh * 9 + u] += wv[u];
        shRed[jh * 9 + 8] += den;
    }
    __syncthreads();
    if (q4 == 3) {
        #pragma unroll
        for (int u = 0; u < 8; ++u) shRed[jh * 9 + u] += wv[u];
        shRed[jh * 9 + 8] += den;
    }
    __syncthreads();                 // loop + swaps + reduction complete

    // ---- P4: coalesced sc_sp dump (2 threads per sparse row); wV -> dead shK
    {
        const int row = t >> 1, pp = t & 1;
        *(float4*)(scsp + (size_t)((size_t)b * 1024 + joff * 16 + row) * 8 + pp * 4) =
            *(const float4*)&shPE[row * 8 + pp * 4];
    }
    if (t < 256) {                   // q4==0 group: finalize its (j,hh)
        const float* rd = &shRed[t * 9];
        const float id = 1.f / rd[8];
        float* wp = &shK[(t >> 3) * 64 + (t & 7) * 8];  // wV[32][64], plain layout
        *(float4*)(wp)     = make_float4(rd[0]*id, rd[1]*id, rd[2]*id, rd[3]*id);
        *(float4*)(wp + 4) = make_float4(rd[4]*id, rd[5]*id, rd[6]*id, rd[7]*id);
    }
    __syncthreads();

    // ---- P5: h_out = wV @ Wo^T + bo. thread = (rl = t>>5, c0 = (t&31)*2), 2 cols
    {
        const int rl = t >> 5;
        const int c0 = (t & 31) * 2;
        float acc[2];
        acc[0] = bo[c0]; acc[1] = bo[c0 + 1];
        #pragma unroll 1
        for (int k0 = 0; k0 < 4; ++k0) {
            float tv[16];
            #pragma unroll
            for (int u = 0; u < 4; ++u) {
                const float4 x = *(const float4*)&shK[rl * 64 + k0 * 16 + u * 4];
                tv[u*4+0] = x.x; tv[u*4+1] = x.y; tv[u*4+2] = x.z; tv[u*4+3] = x.w;
            }
            #pragma unroll
            for (int u = 0; u < 2; ++u) {
                const float* wo = Wo + (c0 + u) * 64 + k0 * 16;
                #pragma unroll
                for (int k = 0; k < 16; ++k)
                    acc[u] = fmaf(tv[k], wo[k], acc[u]);
            }
        }
        float* orow = h_out + (size_t)(b * 64 + joff + rl) * 64 + c0;
        *(float2*)orow = make_float2(acc[0], acc[1]);
    }
}

// prep: M2/bc (fallback) + T[73][64] = [Woe^T ; M2^T ; bc].
__global__ void prep_kernel(const float* __restrict__ Wap, const float* __restrict__ bap,
                            const float* __restrict__ Woe, const float* __restrict__ boe,
                            float* __restrict__ M2, float* __restrict__ Tm, int hasT)
{
    const int tg = blockIdx.x * 64 + threadIdx.x;
    if (tg < 512) {
        const int c = tg >> 3, hq = tg & 7;
        float s = 0.f;
        #pragma unroll 8
        for (int k = 0; k < 64; ++k) s = fmaf(Woe[c * 64 + k], Wap[k * 8 + hq], s);
        M2[tg] = s;
    } else if (tg < 576) {
        const int c = tg - 512;
        float s = boe[c];
        #pragma unroll 8
        for (int k = 0; k < 64; ++k) s = fmaf(bap[k], Woe[c * 64 + k], s);
        M2[512 + c] = s;
    } else if (hasT && tg < 576 + 73 * 64) {
        const int idx = tg - 576;
        const int k = idx >> 6, c = idx & 63;
        float v;
        if (k < 64) {
            v = Woe[c * 64 + k];
        } else if (k < 72) {
            const int hq = k - 64;
            v = 0.f;
            #pragma unroll 8
            for (int kk = 0; kk < 64; ++kk)
                v = fmaf(Woe[c * 64 + kk], Wap[kk * 8 + hq], v);
        } else {
            v = boe[c];
            #pragma unroll 8
            for (int kk = 0; kk < 64; ++kk)
                v = fmaf(bap[kk], Woe[c * 64 + kk], v);
        }
        Tm[k * 64 + c] = v;
    }
}

// eoutT: 4x4 micro-tile GEMM. 256 threads = (rq 0..15, cq 0..15); per k exactly
// 2 bank-spread b128 LDS reads feed 16 independent FMAs. sc folded as k=64..71.
__global__ __launch_bounds__(256, 2) void eoutT_kernel(
    const float* __restrict__ e,
    const float* __restrict__ scsp,
    const float* __restrict__ Tm,      // [73][64]: Woe^T, M2^T, bc
    float* __restrict__ e_out)
{
    __shared__ float shET[72 * 69];   // rows 0..63 e^T, 64..71 sc^T; stride 69
    __shared__ float shTm[73 * 64];   // Tm verbatim (18.7 KB)

    const int t    = threadIdx.x;
    const int base = blockIdx.x * 64;

    {   // coop e-tile load (coalesced) -> transposed LDS store (stride 69: 2-way)
        const int r0 = t >> 2, qq = t & 3;
        const float* ep = e + (size_t)(base + r0) * 64 + qq * 16;
        #pragma unroll
        for (int v = 0; v < 4; ++v) {
            const float4 x = ((const float4*)ep)[v];
            const int c = qq * 16 + v * 4;
            shET[(c + 0) * 69 + r0] = x.x;
            shET[(c + 1) * 69 + r0] = x.y;
            shET[(c + 2) * 69 + r0] = x.z;
            shET[(c + 3) * 69 + r0] = x.w;
        }
    }
    if (t < 128) {   // sc rows -> shET rows 64..71 (transposed)
        const int r = t >> 1, pp = t & 1;
        const float4 s4 = *(const float4*)(scsp + (size_t)(base + r) * 8 + pp * 4);
        shET[(64 + pp * 4 + 0) * 69 + r] = s4.x;
        shET[(64 + pp * 4 + 1) * 69 + r] = s4.y;
        shET[(64 + pp * 4 + 2) * 69 + r] = s4.z;
        shET[(64 + pp * 4 + 3) * 69 + r] = s4.w;
    }
    #pragma unroll
    for (int v = 0; v < 5; ++v) {     // stage Tm: 73*64/4 = 1168 float4
        const int fi = v * 256 + t;
        if (fi < 1168)
            *(float4*)&shTm[fi * 4] = *(const float4*)(Tm + fi * 4);
    }
    __syncthreads();

    const int rq = t >> 4;            // row quad 0..15
    const int cq = t & 15;            // col quad 0..15

    float acc[16];                    // acc[ri*4+cu] = out[rq*4+ri][cq*4+cu]
    {
        const float4 bcv = *(const float4*)&shTm[72 * 64 + cq * 4];
        #pragma unroll
        for (int ri = 0; ri < 4; ++ri) {
            acc[ri*4+0] = bcv.x; acc[ri*4+1] = bcv.y;
            acc[ri*4+2] = bcv.z; acc[ri*4+3] = bcv.w;
        }
    }
    #pragma unroll
    for (int k = 0; k < 72; ++k) {
        const float4 ev = *(const float4*)&shET[k * 69 + rq * 4];   // 4 rows
        const float4 wk = *(const float4*)&shTm[k * 64 + cq * 4];   // 4 cols
        acc[0]  = fmaf(ev.x, wk.x, acc[0]);  acc[1]  = fmaf(ev.x, wk.y, acc[1]);
        acc[2]  = fmaf(ev.x, wk.z, acc[2]);  acc[3]  = fmaf(ev.x, wk.w, acc[3]);
        acc[4]  = fmaf(ev.y, wk.x, acc[4]);  acc[5]  = fmaf(ev.y, wk.y, acc[5]);
        acc[6]  = fmaf(ev.y, wk.z, acc[6]);  acc[7]  = fmaf(ev.y, wk.w, acc[7]);
        acc[8]  = fmaf(ev.z, wk.x, acc[8]);  acc[9]  = fmaf(ev.z, wk.y, acc[9]);
        acc[10] = fmaf(ev.z, wk.z, acc[10]); acc[11] = fmaf(ev.z, wk.w, acc[11]);
        acc[12] = fmaf(ev.w, wk.x, acc[12]); acc[13] = fmaf(ev.w, wk.y, acc[13]);
        acc[14] = fmaf(ev.w, wk.z, acc[14]); acc[15] = fmaf(ev.w, wk.w, acc[15]);
    }
    #pragma unroll
    for (int ri = 0; ri < 4; ++ri) {
        float* orow = e_out + (size_t)(base + rq * 4 + ri) * 64 + cq * 4;
        *(float4*)orow = make_float4(acc[ri*4+0], acc[ri*4+1], acc[ri*4+2], acc[ri*4+3]);
    }
}

// Fallback eout (r10 shape) if d_ws can't hold T.
__global__ __launch_bounds__(256, 2) void eout_kernel(
    const float* __restrict__ e,
    const float* __restrict__ scsp,
    const float* __restrict__ Woe,
    const float* __restrict__ M2g,
    float* __restrict__ e_out)
{
    __shared__ float shE[64 * 64];
    __shared__ float shS[64 * 8];
    const int t    = threadIdx.x;
    const int base = blockIdx.x * 64;
    {
        const int r = t >> 2, qq = t & 3;
        const float* ep = e + (size_t)(base + r) * 64 + qq * 16;
        #pragma unroll
        for (int u = 0; u < 4; ++u) {
            const float4 x = ((const float4*)ep)[u];
            const int cc = qq * 4 + u;
            *(float4*)&shE[r * 64 + ((cc ^ (r & 15)) << 2)] = x;
        }
    }
    if (t < 128) {
        const int r = t >> 1, pp = t & 1;
        *(float4*)&shS[r * 8 + pp * 4] =
            *(const float4*)(scsp + (size_t)(base + r) * 8 + pp * 4);
    }
    __syncthreads();
    const int w = __builtin_amdgcn_readfirstlane(t >> 6);
    const int r = t & 63;
    float sc[8];
    {
        const float4 a  = *(const float4*)&shS[r * 8];
        const float4 c4 = *(const float4*)&shS[r * 8 + 4];
        sc[0]=a.x; sc[1]=a.y; sc[2]=a.z; sc[3]=a.w;
        sc[4]=c4.x; sc[5]=c4.y; sc[6]=c4.z; sc[7]=c4.w;
    }
    float acc[16];
    #pragma unroll
    for (int u = 0; u < 16; ++u) {
        const int c = w * 16 + u;
        float s = M2g[512 + c];
        #pragma unroll
        for (int hq = 0; hq < 8; ++hq)
            s = fmaf(sc[hq], M2g[c * 8 + hq], s);
        acc[u] = s;
    }
    #pragma unroll
    for (int k0 = 0; k0 < 4; ++k0) {
        float ev[16];
        #pragma unroll
        for (int v = 0; v < 4; ++v) {
            const int cc = k0 * 4 + v;
            const float4 x = *(const float4*)&shE[r * 64 + ((cc ^ (r & 15)) << 2)];
            ev[v*4+0] = x.x; ev[v*4+1] = x.y; ev[v*4+2] = x.z; ev[v*4+3] = x.w;
        }
        #pragma unroll
        for (int u = 0; u < 16; ++u) {
            const float* wr = Woe + (w * 16 + u) * 64 + k0 * 16;
            #pragma unroll
            for (int k = 0; k < 16; ++k)
                acc[u] = fmaf(ev[k], wr[k], acc[u]);
        }
    }
    float* orow = e_out + (size_t)(base + r) * 64 + w * 16;
    #pragma unroll
    for (int u = 0; u < 4; ++u)
        *(float4*)&orow[u * 4] =
            make_float4(acc[u*4+0], acc[u*4+1], acc[u*4+2], acc[u*4+3]);
}

extern "C" void kernel_launch(void* const* d_in, const int* in_sizes, int n_in,
                              void* d_out, int out_size, void* d_ws, size_t ws_size,
                              hipStream_t stream) {
    const float* h    = (const float*)d_in[0];
    const float* e    = (const float*)d_in[1];
    const float* adj2 = (const float*)d_in[2];
    const float* rel  = (const float*)d_in[3];
    const float* Wq   = (const float*)d_in[4];  const float* bq  = (const float*)d_in[5];
    const float* Wk   = (const float*)d_in[6];  const float* bk  = (const float*)d_in[7];
    const float* Wv   = (const float*)d_in[8];  const float* bv  = (const float*)d_in[9];
    const float* Wpe  = (const float*)d_in[10]; const float* bpe = (const float*)d_in[11];
    const float* Wap  = (const float*)d_in[12]; const float* bap = (const float*)d_in[13];
    const float* Wo   = (const float*)d_in[14]; const float* bo  = (const float*)d_in[15];
    const float* Woe  = (const float*)d_in[16]; const float* boe = (const float*)d_in[17];

    float* out  = (float*)d_out;
    float* hout = out;                        // [16384*64]
    float* eout = out + 16384 * 64;           // [262144*64], staging (dead at eout time)
    float* Qs   = eout;                       // 1048576 floats
    float* Ks   = eout + 1048576;
    float* Vs   = eout + 2097152;
    float* PEs  = eout + 3145728;             // 2097152 floats
    float* ws   = (float*)d_ws;
    float* scsp = ws;                         // [262144*8]
    float* M2g  = ws + 2097152;               // [576]
    float* Tm   = ws + 2098176;               // [73*64]
    const int hasT = (ws_size >= (size_t)(2098176 + 73 * 64) * sizeof(float)) ? 1 : 0;

    prep_kernel<<<dim3(82), dim3(64), 0, stream>>>(Wap, bap, Woe, boe, M2g, Tm, hasT);
    qkvpe_kernel<<<dim3(768), dim3(512), 0, stream>>>(
        h, e, Wq, bq, Wk, bk, Wv, bv, Wpe, bpe, Qs, Ks, Vs, PEs);
    attn_kernel<<<dim3(512), dim3(1024), 0, stream>>>(
        Qs, Ks, Vs, PEs, adj2, rel, Wo, bo, hout, scsp);
    if (hasT)
        eoutT_kernel<<<dim3(4096), dim3(256), 0, stream>>>(e, scsp, Tm, eout);
    else
        eout_kernel<<<dim3(4096), dim3(256), 0, stream>>>(e, scsp, Woe, M2g, eout);
}

// Round 14
// 130.754 us; speedup vs baseline: 1.3040x; 1.0014x over previous
//
#include <hip/hip_runtime.h>

// Geometry: G=256 graphs x 64 nodes, H=8 heads x D=8, IN_DIM=EDGE_DIM=64
// EF = 1048576 full edges, ES = 262144 sparse edges.
// edge f = b*4096 + i*64 + j (src=i, dst=j); sparse s = b*1024 + j*16 + k, i=(j+1+k)&63.
//
// Staging: d_out eout region: Qs @0, Ks @1048576, Vs @2097152, PEs @3145728.
//          h_out region doubles as wVg (normalized wV) between attn and hout.
//          d_ws: scsp [262144*8] @0, M2 [576] @2097152, T [73*64] @2098176.
// NOTE launch_bounds: VGPR cap = 2048/(threads/64 * minwaves); spill alarm =
// WRITE_SIZE blowup (r2/r3/r12).
// NOTE r13 meta-result: attn 58-66us invariant across occupancy/coalescing/
// conflict fixes, all counters idle. Only zero-LDS zero-barrier streaming
// kernels (qkvpe: 88MB @ 4.6TB/s) run at machine speed. This round: attn
// rewritten in that shape (thread owns full (j,hh) reduction; no LDS, no
// syncthreads, sparse handled by m-loop split with static sc[] indices).

// qkv half (blocks 0..255) + pe half (blocks 256..767), independent.
__global__ __launch_bounds__(512, 2) void qkvpe_kernel(
    const float* __restrict__ h,
    const float* __restrict__ e,
    const float* __restrict__ Wq, const float* __restrict__ bq,
    const float* __restrict__ Wk, const float* __restrict__ bk,
    const float* __restrict__ Wv, const float* __restrict__ bv,
    const float* __restrict__ Wpe, const float* __restrict__ bpe,
    float* __restrict__ Qs, float* __restrict__ Ks, float* __restrict__ Vs,
    float* __restrict__ PEs)
{
    const int t = threadIdx.x;
    if (blockIdx.x < 256) {
        const int b    = blockIdx.x;
        const int lane = t & 63;
        const int wu   = __builtin_amdgcn_readfirstlane(t >> 6);   // 8 cols per wave
        const float* hrow = h + (size_t)(b * 64 + lane) * 64;
        float accQ[8], accK[8], accV[8];
        #pragma unroll
        for (int cc = 0; cc < 8; ++cc) {
            const int c = wu * 8 + cc;
            accQ[cc] = bq[c]; accK[cc] = bk[c]; accV[cc] = bv[c];
        }
        #pragma unroll 1
        for (int k0 = 0; k0 < 4; ++k0) {
            float hv[16];
            #pragma unroll
            for (int u = 0; u < 4; ++u) {
                const float4 x = ((const float4*)hrow)[k0 * 4 + u];
                hv[u*4+0] = x.x; hv[u*4+1] = x.y; hv[u*4+2] = x.z; hv[u*4+3] = x.w;
            }
            #pragma unroll
            for (int cc = 0; cc < 8; ++cc) {
                const int c = wu * 8 + cc;
                const float* wq  = Wq + c * 64 + k0 * 16;   // wave-uniform -> s_load
                const float* wk  = Wk + c * 64 + k0 * 16;
                const float* wvp = Wv + c * 64 + k0 * 16;
                #pragma unroll
                for (int k = 0; k < 16; ++k) {
                    accQ[cc] = fmaf(hv[k], wq[k],  accQ[cc]);
                    accK[cc] = fmaf(hv[k], wk[k],  accK[cc]);
                    accV[cc] = fmaf(hv[k], wvp[k], accV[cc]);
                }
            }
        }
        const size_t o = (size_t)(b * 64 + lane) * 64 + wu * 8;
        *(float4*)(Qs + o)     = make_float4(accQ[0], accQ[1], accQ[2], accQ[3]);
        *(float4*)(Qs + o + 4) = make_float4(accQ[4], accQ[5], accQ[6], accQ[7]);
        *(float4*)(Ks + o)     = make_float4(accK[0], accK[1], accK[2], accK[3]);
        *(float4*)(Ks + o + 4) = make_float4(accK[4], accK[5], accK[6], accK[7]);
        *(float4*)(Vs + o)     = make_float4(accV[0], accV[1], accV[2], accV[3]);
        *(float4*)(Vs + o + 4) = make_float4(accV[4], accV[5], accV[6], accV[7]);
    } else {
        const int row = (blockIdx.x - 256) * 512 + t;      // 0..ES-1
        const float* erow = e + (size_t)row * 64;
        float acc[8];
        #pragma unroll
        for (int h2 = 0; h2 < 8; ++h2) acc[h2] = bpe[h2];
        #pragma unroll 1
        for (int k0 = 0; k0 < 4; ++k0) {
            float ev[16];
            #pragma unroll
            for (int u = 0; u < 4; ++u) {
                const float4 x = ((const float4*)erow)[k0 * 4 + u];
                ev[u*4+0] = x.x; ev[u*4+1] = x.y; ev[u*4+2] = x.z; ev[u*4+3] = x.w;
            }
            #pragma unroll
            for (int h2 = 0; h2 < 8; ++h2) {
                const float* wp = Wpe + h2 * 64 + k0 * 16;  // uniform -> s_load
                #pragma unroll
                for (int k = 0; k < 16; ++k)
                    acc[h2] = fmaf(ev[k], wp[k], acc[h2]);
            }
        }
        float* p0 = PEs + (size_t)row * 8;
        *(float4*)(p0)     = make_float4(acc[0], acc[1], acc[2], acc[3]);
        *(float4*)(p0 + 4) = make_float4(acc[4], acc[5], acc[6], acc[7]);
    }
}

// attn streaming: NO LDS, NO barriers. 512 blocks x 256 threads; thread =
// (j = joff + t>>3, hh = t&7) owns the full 64-i reduction in registers.
// m-loop with i = (j+1+m)&63: m<16 are the sparse edges (static sc[m] index).
// K/V per graph = 32KB, L1/L2-hot; rel is the HBM stream.
__global__ __launch_bounds__(256, 2) void attn_kernel(
    const float* __restrict__ Qs, const float* __restrict__ Ks,
    const float* __restrict__ Vs, const float* __restrict__ PEs,
    const float* __restrict__ adj2,
    const float* __restrict__ rel,
    float* __restrict__ wVg,          // [16384*64] = h_out region (normalized wV)
    float* __restrict__ scsp)
{
    const int b2   = blockIdx.x;
    const int b    = b2 >> 1;
    const int joff = (b2 & 1) << 5;
    const int t    = threadIdx.x;
    const int j    = joff + (t >> 3);        // 0..63
    const int hh   = t & 7;

    const float* kB   = Ks + (size_t)b * 4096 + hh * 8;      // + i*64
    const float* vB   = Vs + (size_t)b * 4096 + hh * 8;
    const float* relP = rel + ((size_t)b * 4096 + j) * 8 + hh;   // + i*512
    const float* adjP = adj2 + (size_t)b * 4096 + j;             // + i*64
    const float* peP  = PEs + ((size_t)b * 1024 + j * 16) * 8 + hh;  // + m*8

    float q[8];
    {
        const float* qp = Qs + (size_t)(b * 64 + j) * 64 + hh * 8;
        const float4 a = *(const float4*)qp;
        const float4 c = *(const float4*)(qp + 4);
        q[0]=a.x; q[1]=a.y; q[2]=a.z; q[3]=a.w;
        q[4]=c.x; q[5]=c.y; q[6]=c.z; q[7]=c.w;
    }

    float den = 0.f;
    float wv[8] = {0.f,0.f,0.f,0.f,0.f,0.f,0.f,0.f};
    float sc[16];
    const float inv_scale = 0.35355339059327379f;  // 1/sqrt(8)

    // ---- sparse edges first: m = 0..15, i = (j+1+m)&63, sc[m] static
    #pragma unroll
    for (int m = 0; m < 16; ++m) {
        const int i = (j + 1 + m) & 63;
        const float4 kA = *(const float4*)(kB + i * 64);
        const float4 kBv = *(const float4*)(kB + i * 64 + 4);
        const float rp = relP[(size_t)i * 512];
        const float a2 = adjP[(size_t)i * 64];
        const float pe = peP[m * 8];
        float s = kA.x * q[0];
        s = fmaf(kA.y, q[1], s); s = fmaf(kA.z, q[2], s); s = fmaf(kA.w, q[3], s);
        s = fmaf(kBv.x, q[4], s); s = fmaf(kBv.y, q[5], s); s = fmaf(kBv.z, q[6], s);
        s = fmaf(kBv.w, q[7], s);
        s = fmaf(s * inv_scale, a2, rp);      // raw score (pre proj_e)
        sc[m] = s;
        s += pe;                              // softmax sees sc + proj_e
        s = fminf(fmaxf(s, -5.f), 5.f);
        const float ex = __expf(s);
        den += ex;
        const float4 vA = *(const float4*)(vB + i * 64);
        const float4 vBv = *(const float4*)(vB + i * 64 + 4);
        wv[0] = fmaf(ex, vA.x, wv[0]); wv[1] = fmaf(ex, vA.y, wv[1]);
        wv[2] = fmaf(ex, vA.z, wv[2]); wv[3] = fmaf(ex, vA.w, wv[3]);
        wv[4] = fmaf(ex, vBv.x, wv[4]); wv[5] = fmaf(ex, vBv.y, wv[5]);
        wv[6] = fmaf(ex, vBv.z, wv[6]); wv[7] = fmaf(ex, vBv.w, wv[7]);
    }
    // ---- remaining 48 edges: m = 16..63 (includes i=j at m=63), no branch
    #pragma unroll 8
    for (int m = 16; m < 64; ++m) {
        const int i = (j + 1 + m) & 63;
        const float4 kA = *(const float4*)(kB + i * 64);
        const float4 kBv = *(const float4*)(kB + i * 64 + 4);
        const float rp = relP[(size_t)i * 512];
        const float a2 = adjP[(size_t)i * 64];
        float s = kA.x * q[0];
        s = fmaf(kA.y, q[1], s); s = fmaf(kA.z, q[2], s); s = fmaf(kA.w, q[3], s);
        s = fmaf(kBv.x, q[4], s); s = fmaf(kBv.y, q[5], s); s = fmaf(kBv.z, q[6], s);
        s = fmaf(kBv.w, q[7], s);
        s = fmaf(s * inv_scale, a2, rp);
        s = fminf(fmaxf(s, -5.f), 5.f);
        const float ex = __expf(s);
        den += ex;
        const float4 vA = *(const float4*)(vB + i * 64);
        const float4 vBv = *(const float4*)(vB + i * 64 + 4);
        wv[0] = fmaf(ex, vA.x, wv[0]); wv[1] = fmaf(ex, vA.y, wv[1]);
        wv[2] = fmaf(ex, vA.z, wv[2]); wv[3] = fmaf(ex, vA.w, wv[3]);
        wv[4] = fmaf(ex, vBv.x, wv[4]); wv[5] = fmaf(ex, vBv.y, wv[5]);
        wv[6] = fmaf(ex, vBv.z, wv[6]); wv[7] = fmaf(ex, vBv.w, wv[7]);
    }

    // ---- sc_sp dump (16 stores, 32B-chunk pattern per wave-store)
    float* sp = scsp + ((size_t)b * 1024 + j * 16) * 8 + hh;
    #pragma unroll
    for (int m = 0; m < 16; ++m) sp[m * 8] = sc[m];

    // ---- normalized wV out (wave writes 2KB contiguous)
    const float id = 1.f / den;
    float* wp = wVg + (size_t)(b * 64 + j) * 64 + hh * 8;
    *(float4*)(wp)     = make_float4(wv[0]*id, wv[1]*id, wv[2]*id, wv[3]*id);
    *(float4*)(wp + 4) = make_float4(wv[4]*id, wv[5]*id, wv[6]*id, wv[7]*id);
}

// hout: h_out = wVg @ Wo^T + bo, 4x4 micro-tile, wVg lives IN h_out region
// (rows staged to LDS before overwrite -> safe in-place).
__global__ __launch_bounds__(256, 2) void hout_kernel(
    const float* __restrict__ wVg,
    const float* __restrict__ Wo, const float* __restrict__ bo,
    float* __restrict__ h_out)
{
    __shared__ float shWT[64 * 69];   // [r][d] transposed: stride 69
    __shared__ float shWoT[64 * 65];  // [k][c] = Wo[c][k], stride 65

    const int t    = threadIdx.x;
    const int base = blockIdx.x * 64;

    {   // stage wVg tile transposed (coalesced read)
        const int r0 = t >> 2, qq = t & 3;
        const float* ep = wVg + (size_t)(base + r0) * 64 + qq * 16;
        #pragma unroll
        for (int v = 0; v < 4; ++v) {
            const float4 x = ((const float4*)ep)[v];
            const int c = qq * 16 + v * 4;
            shWT[(c + 0) * 69 + r0] = x.x;
            shWT[(c + 1) * 69 + r0] = x.y;
            shWT[(c + 2) * 69 + r0] = x.z;
            shWT[(c + 3) * 69 + r0] = x.w;
        }
    }
    {   // stage Wo transposed (coalesced read)
        const int c0 = t >> 2, qq = t & 3;
        const float* wp = Wo + c0 * 64 + qq * 16;
        #pragma unroll
        for (int v = 0; v < 4; ++v) {
            const float4 x = ((const float4*)wp)[v];
            const int k = qq * 16 + v * 4;
            shWoT[(k + 0) * 65 + c0] = x.x;
            shWoT[(k + 1) * 65 + c0] = x.y;
            shWoT[(k + 2) * 65 + c0] = x.z;
            shWoT[(k + 3) * 65 + c0] = x.w;
        }
    }
    __syncthreads();

    const int rq = t >> 4;            // row quad 0..15
    const int cq = t & 15;            // col quad 0..15
    float acc[16];
    {
        const float4 bv = *(const float4*)(bo + cq * 4);
        #pragma unroll
        for (int ri = 0; ri < 4; ++ri) {
            acc[ri*4+0] = bv.x; acc[ri*4+1] = bv.y;
            acc[ri*4+2] = bv.z; acc[ri*4+3] = bv.w;
        }
    }
    #pragma unroll
    for (int k = 0; k < 64; ++k) {
        const float4 ev = *(const float4*)&shWT[k * 69 + rq * 4];
        const float4 wk = *(const float4*)&shWoT[k * 65 + cq * 4];
        acc[0]  = fmaf(ev.x, wk.x, acc[0]);  acc[1]  = fmaf(ev.x, wk.y, acc[1]);
        acc[2]  = fmaf(ev.x, wk.z, acc[2]);  acc[3]  = fmaf(ev.x, wk.w, acc[3]);
        acc[4]  = fmaf(ev.y, wk.x, acc[4]);  acc[5]  = fmaf(ev.y, wk.y, acc[5]);
        acc[6]  = fmaf(ev.y, wk.z, acc[6]);  acc[7]  = fmaf(ev.y, wk.w, acc[7]);
        acc[8]  = fmaf(ev.z, wk.x, acc[8]);  acc[9]  = fmaf(ev.z, wk.y, acc[9]);
        acc[10] = fmaf(ev.z, wk.z, acc[10]); acc[11] = fmaf(ev.z, wk.w, acc[11]);
        acc[12] = fmaf(ev.w, wk.x, acc[12]); acc[13] = fmaf(ev.w, wk.y, acc[13]);
        acc[14] = fmaf(ev.w, wk.z, acc[14]); acc[15] = fmaf(ev.w, wk.w, acc[15]);
    }
    #pragma unroll
    for (int ri = 0; ri < 4; ++ri) {
        float* orow = h_out + (size_t)(base + rq * 4 + ri) * 64 + cq * 4;
        *(float4*)orow = make_float4(acc[ri*4+0], acc[ri*4+1], acc[ri*4+2], acc[ri*4+3]);
    }
}

// prep: M2/bc (fallback) + T[73][64] = [Woe^T ; M2^T ; bc].
__global__ void prep_kernel(const float* __restrict__ Wap, const float* __restrict__ bap,
                            const float* __restrict__ Woe, const float* __restrict__ boe,
                            float* __restrict__ M2, float* __restrict__ Tm, int hasT)
{
    const int tg = blockIdx.x * 64 + threadIdx.x;
    if (tg < 512) {
        const int c = tg >> 3, hq = tg & 7;
        float s = 0.f;
        #pragma unroll 8
        for (int k = 0; k < 64; ++k) s = fmaf(Woe[c * 64 + k], Wap[k * 8 + hq], s);
        M2[tg] = s;
    } else if (tg < 576) {
        const int c = tg - 512;
        float s = boe[c];
        #pragma unroll 8
        for (int k = 0; k < 64; ++k) s = fmaf(bap[k], Woe[c * 64 + k], s);
        M2[512 + c] = s;
    } else if (hasT && tg < 576 + 73 * 64) {
        const int idx = tg - 576;
        const int k = idx >> 6, c = idx & 63;
        float v;
        if (k < 64) {
            v = Woe[c * 64 + k];
        } else if (k < 72) {
            const int hq = k - 64;
            v = 0.f;
            #pragma unroll 8
            for (int kk = 0; kk < 64; ++kk)
                v = fmaf(Woe[c * 64 + kk], Wap[kk * 8 + hq], v);
        } else {
            v = boe[c];
            #pragma unroll 8
            for (int kk = 0; kk < 64; ++kk)
                v = fmaf(bap[kk], Woe[c * 64 + kk], v);
        }
        Tm[k * 64 + c] = v;
    }
}

// eoutT: 4x4 micro-tile GEMM (r13, DO NOT PERTURB). sc folded as k=64..71.
__global__ __launch_bounds__(256, 2) void eoutT_kernel(
    const float* __restrict__ e,
    const float* __restrict__ scsp,
    const float* __restrict__ Tm,      // [73][64]: Woe^T, M2^T, bc
    float* __restrict__ e_out)
{
    __shared__ float shET[72 * 69];   // rows 0..63 e^T, 64..71 sc^T; stride 69
    __shared__ float shTm[73 * 64];   // Tm verbatim (18.7 KB)

    const int t    = threadIdx.x;
    const int base = blockIdx.x * 64;

    {   // coop e-tile load (coalesced) -> transposed LDS store (stride 69)
        const int r0 = t >> 2, qq = t & 3;
        const float* ep = e + (size_t)(base + r0) * 64 + qq * 16;
        #pragma unroll
        for (int v = 0; v < 4; ++v) {
            const float4 x = ((const float4*)ep)[v];
            const int c = qq * 16 + v * 4;
            shET[(c + 0) * 69 + r0] = x.x;
            shET[(c + 1) * 69 + r0] = x.y;
            shET[(c + 2) * 69 + r0] = x.z;
            shET[(c + 3) * 69 + r0] = x.w;
        }
    }
    if (t < 128) {   // sc rows -> shET rows 64..71 (transposed)
        const int r = t >> 1, pp = t & 1;
        const float4 s4 = *(const float4*)(scsp + (size_t)(base + r) * 8 + pp * 4);
        shET[(64 + pp * 4 + 0) * 69 + r] = s4.x;
        shET[(64 + pp * 4 + 1) * 69 + r] = s4.y;
        shET[(64 + pp * 4 + 2) * 69 + r] = s4.z;
        shET[(64 + pp * 4 + 3) * 69 + r] = s4.w;
    }
    #pragma unroll
    for (int v = 0; v < 5; ++v) {     // stage Tm: 73*64/4 = 1168 float4
        const int fi = v * 256 + t;
        if (fi < 1168)
            *(float4*)&shTm[fi * 4] = *(const float4*)(Tm + fi * 4);
    }
    __syncthreads();

    const int rq = t >> 4;            // row quad 0..15
    const int cq = t & 15;            // col quad 0..15
    float acc[16];
    {
        const float4 bcv = *(const float4*)&shTm[72 * 64 + cq * 4];
        #pragma unroll
        for (int ri = 0; ri < 4; ++ri) {
            acc[ri*4+0] = bcv.x; acc[ri*4+1] = bcv.y;
            acc[ri*4+2] = bcv.z; acc[ri*4+3] = bcv.w;
        }
    }
    #pragma unroll
    for (int k = 0; k < 72; ++k) {
        const float4 ev = *(const float4*)&shET[k * 69 + rq * 4];   // 4 rows
        const float4 wk = *(const float4*)&shTm[k * 64 + cq * 4];   // 4 cols
        acc[0]  = fmaf(ev.x, wk.x, acc[0]);  acc[1]  = fmaf(ev.x, wk.y, acc[1]);
        acc[2]  = fmaf(ev.x, wk.z, acc[2]);  acc[3]  = fmaf(ev.x, wk.w, acc[3]);
        acc[4]  = fmaf(ev.y, wk.x, acc[4]);  acc[5]  = fmaf(ev.y, wk.y, acc[5]);
        acc[6]  = fmaf(ev.y, wk.z, acc[6]);  acc[7]  = fmaf(ev.y, wk.w, acc[7]);
        acc[8]  = fmaf(ev.z, wk.x, acc[8]);  acc[9]  = fmaf(ev.z, wk.y, acc[9]);
        acc[10] = fmaf(ev.z, wk.z, acc[10]); acc[11] = fmaf(ev.z, wk.w, acc[11]);
        acc[12] = fmaf(ev.w, wk.x, acc[12]); acc[13] = fmaf(ev.w, wk.y, acc[13]);
        acc[14] = fmaf(ev.w, wk.z, acc[14]); acc[15] = fmaf(ev.w, wk.w, acc[15]);
    }
    #pragma unroll
    for (int ri = 0; ri < 4; ++ri) {
        float* orow = e_out + (size_t)(base + rq * 4 + ri) * 64 + cq * 4;
        *(float4*)orow = make_float4(acc[ri*4+0], acc[ri*4+1], acc[ri*4+2], acc[ri*4+3]);
    }
}

// Fallback eout if d_ws can't hold T.
__global__ __launch_bounds__(256, 2) void eout_kernel(
    const float* __restrict__ e,
    const float* __restrict__ scsp,
    const float* __restrict__ Woe,
    const float* __restrict__ M2g,
    float* __restrict__ e_out)
{
    __shared__ float shE[64 * 64];
    __shared__ float shS[64 * 8];
    const int t    = threadIdx.x;
    const int base = blockIdx.x * 64;
    {
        const int r = t >> 2, qq = t & 3;
        const float* ep = e + (size_t)(base + r) * 64 + qq * 16;
        #pragma unroll
        for (int u = 0; u < 4; ++u) {
            const float4 x = ((const float4*)ep)[u];
            const int cc = qq * 4 + u;
            *(float4*)&shE[r * 64 + ((cc ^ (r & 15)) << 2)] = x;
        }
    }
    if (t < 128) {
        const int r = t >> 1, pp = t & 1;
        *(float4*)&shS[r * 8 + pp * 4] =
            *(const float4*)(scsp + (size_t)(base + r) * 8 + pp * 4);
    }
    __syncthreads();
    const int w = __builtin_amdgcn_readfirstlane(t >> 6);
    const int r = t & 63;
    float sc[8];
    {
        const float4 a  = *(const float4*)&shS[r * 8];
        const float4 c4 = *(const float4*)&shS[r * 8 + 4];
        sc[0]=a.x; sc[1]=a.y; sc[2]=a.z; sc[3]=a.w;
        sc[4]=c4.x; sc[5]=c4.y; sc[6]=c4.z; sc[7]=c4.w;
    }
    float acc[16];
    #pragma unroll
    for (int u = 0; u < 16; ++u) {
        const int c = w * 16 + u;
        float s = M2g[512 + c];
        #pragma unroll
        for (int hq = 0; hq < 8; ++hq)
            s = fmaf(sc[hq], M2g[c * 8 + hq], s);
        acc[u] = s;
    }
    #pragma unroll
    for (int k0 = 0; k0 < 4; ++k0) {
        float ev[16];
        #pragma unroll
        for (int v = 0; v < 4; ++v) {
            const int cc = k0 * 4 + v;
            const float4 x = *(const float4*)&shE[r * 64 + ((cc ^ (r & 15)) << 2)];
            ev[v*4+0] = x.x; ev[v*4+1] = x.y; ev[v*4+2] = x.z; ev[v*4+3] = x.w;
        }
        #pragma unroll
        for (int u = 0; u < 16; ++u) {
            const float* wr = Woe + (w * 16 + u) * 64 + k0 * 16;
            #pragma unroll
            for (int k = 0; k < 16; ++k)
                acc[u] = fmaf(ev[k], wr[k], acc[u]);
        }
    }
    float* orow = e_out + (size_t)(base + r) * 64 + w * 16;
    #pragma unroll
    for (int u = 0; u < 4; ++u)
        *(float4*)&orow[u * 4] =
            make_float4(acc[u*4+0], acc[u*4+1], acc[u*4+2], acc[u*4+3]);
}

extern "C" void kernel_launch(void* const* d_in, const int* in_sizes, int n_in,
                              void* d_out, int out_size, void* d_ws, size_t ws_size,
                              hipStream_t stream) {
    const float* h    = (const float*)d_in[0];
    const float* e    = (const float*)d_in[1];
    const float* adj2 = (const float*)d_in[2];
    const float* rel  = (const float*)d_in[3];
    const float* Wq   = (const float*)d_in[4];  const float* bq  = (const float*)d_in[5];
    const float* Wk   = (const float*)d_in[6];  const float* bk  = (const float*)d_in[7];
    const float* Wv   = (const float*)d_in[8];  const float* bv  = (const float*)d_in[9];
    const float* Wpe  = (const float*)d_in[10]; const float* bpe = (const float*)d_in[11];
    const float* Wap  = (const float*)d_in[12]; const float* bap = (const float*)d_in[13];
    const float* Wo   = (const float*)d_in[14]; const float* bo  = (const float*)d_in[15];
    const float* Woe  = (const float*)d_in[16]; const float* boe = (const float*)d_in[17];

    float* out  = (float*)d_out;
    float* hout = out;                        // [16384*64]; also wVg between kernels
    float* eout = out + 16384 * 64;           // [262144*64], staging (dead at eout time)
    float* Qs   = eout;                       // 1048576 floats
    float* Ks   = eout + 1048576;
    float* Vs   = eout + 2097152;
    float* PEs  = eout + 3145728;             // 2097152 floats
    float* ws   = (float*)d_ws;
    float* scsp = ws;                         // [262144*8]
    float* M2g  = ws + 2097152;               // [576]
    float* Tm   = ws + 2098176;               // [73*64]
    const int hasT = (ws_size >= (size_t)(2098176 + 73 * 64) * sizeof(float)) ? 1 : 0;

    prep_kernel<<<dim3(82), dim3(64), 0, stream>>>(Wap, bap, Woe, boe, M2g, Tm, hasT);
    qkvpe_kernel<<<dim3(768), dim3(512), 0, stream>>>(
        h, e, Wq, bq, Wk, bk, Wv, bv, Wpe, bpe, Qs, Ks, Vs, PEs);
    attn_kernel<<<dim3(512), dim3(256), 0, stream>>>(
        Qs, Ks, Vs, PEs, adj2, rel, hout /*wVg*/, scsp);
    hout_kernel<<<dim3(256), dim3(256), 0, stream>>>(hout, Wo, bo, hout);
    if (hasT)
        eoutT_kernel<<<dim3(4096), dim3(256), 0, stream>>>(e, scsp, Tm, eout);
    else
        eout_kernel<<<dim3(4096), dim3(256), 0, stream>>>(e, scsp, Woe, M2g, eout);
}